// Round 1
// baseline (625.348 us; speedup 1.0000x reference)
//
#include <hip/hip_runtime.h>

constexpr int BB   = 128;   // batch
constexpr int NSUP = 25;    // support samples
constexpr int NWAY = 5;
constexpr int NTOT = 125;   // NSUP*NWAY
constexpr int NQ   = 75;
constexpr int DIM  = 2560;
constexpr int MAXIT = 15;

#define FMA4(acc, zz, v)                     \
  acc.x = fmaf(zz, v.x, acc.x);              \
  acc.y = fmaf(zz, v.y, acc.y);              \
  acc.z = fmaf(zz, v.z, acc.z);              \
  acc.w = fmaf(zz, v.w, acc.w)

#define DOT4(a, u, vv) a += u.x*vv.x + u.y*vv.y + u.z*vv.z + u.w*vv.w

// ---------------------------------------------------------------------------
// Kernel A: K[b] = support[b] @ support[b]^T, split over 2 d-halves.
// Kpart layout: [half][B][625]
// ---------------------------------------------------------------------------
__global__ __launch_bounds__(256) void k_gram(const float* __restrict__ sup,
                                              float* __restrict__ Kpart) {
  const int b    = blockIdx.x;
  const int half = blockIdx.y;
  const int tid  = threadIdx.x;
  const int wv   = tid >> 6;
  const int ln   = tid & 63;

  __shared__ float tile[28][260];     // 25 rows + 3 zero pad rows, 256 cols + pad
  __shared__ float accb[4][49][16];

  // zero the 3 pad rows once
  for (int c = tid; c < 3 * 260; c += 256) tile[25 + c / 260][c % 260] = 0.0f;

  const float* S = sup + (size_t)b * NSUP * DIM + half * 1280;

  float acc[4][4];
#pragma unroll
  for (int x = 0; x < 4; ++x)
#pragma unroll
    for (int y = 0; y < 4; ++y) acc[x][y] = 0.0f;

  const int ti = ln / 7, tj = ln % 7;   // valid when ln < 49
  const int i0 = 4 * ti, j0 = 4 * tj;

  for (int ch = 0; ch < 5; ++ch) {
    __syncthreads();  // previous chunk fully consumed (and pad-fill done)
    // stage 25 x 256 floats
    for (int q = tid; q < 1600; q += 256) {
      int rr = q >> 6, c4 = q & 63;
      float4 v = *(const float4*)(S + rr * DIM + ch * 256 + 4 * c4);
      *(float4*)&tile[rr][4 * c4] = v;
    }
    __syncthreads();
    if (ln < 49) {
#pragma unroll
      for (int c = 0; c < 16; ++c) {
        const int d4 = (wv * 16 + c) * 4;
        float4 av[4], bv[4];
#pragma unroll
        for (int x = 0; x < 4; ++x) av[x] = *(const float4*)&tile[i0 + x][d4];
#pragma unroll
        for (int y = 0; y < 4; ++y) bv[y] = *(const float4*)&tile[j0 + y][d4];
#pragma unroll
        for (int x = 0; x < 4; ++x)
#pragma unroll
          for (int y = 0; y < 4; ++y) {
            acc[x][y] += av[x].x * bv[y].x + av[x].y * bv[y].y +
                         av[x].z * bv[y].z + av[x].w * bv[y].w;
          }
      }
    }
  }

  if (ln < 49) {
#pragma unroll
    for (int x = 0; x < 4; ++x)
#pragma unroll
      for (int y = 0; y < 4; ++y) accb[wv][ln][x * 4 + y] = acc[x][y];
  }
  __syncthreads();

  for (int p = tid; p < 625; p += 256) {
    int i = p / 25, j = p % 25;
    int l = (i / 4) * 7 + (j / 4);
    int s = (i % 4) * 4 + (j % 4);
    float v = accb[0][l][s] + accb[1][l][s] + accb[2][l][s] + accb[3][l][s];
    Kpart[((size_t)half * BB + b) * 625 + p] = v;
  }
}

// ---------------------------------------------------------------------------
// block reductions (128 threads, 2 waves)
// ---------------------------------------------------------------------------
__device__ __forceinline__ float block_reduce_sum(float v, float* red, float* scal, int tid) {
  red[tid] = v;
  __syncthreads();
  if (tid < 64) {
    float x = red[tid] + red[tid + 64];
#pragma unroll
    for (int off = 32; off; off >>= 1) x += __shfl_xor(x, off);
    if (tid == 0) scal[0] = x;
  }
  __syncthreads();
  return scal[0];
}

__device__ __forceinline__ float block_reduce_min(float v, float* red, float* scal, int tid) {
  red[tid] = v;
  __syncthreads();
  if (tid < 64) {
    float x = fminf(red[tid], red[tid + 64]);
#pragma unroll
    for (int off = 32; off; off >>= 1) x = fminf(x, __shfl_xor(x, off));
    if (tid == 0) scal[0] = x;
  }
  __syncthreads();
  return scal[0];
}

// ---------------------------------------------------------------------------
// Kernel B: Mehrotra predictor-corrector IPM, one block per batch element.
// Exploits G+diag = way-block-diagonal: 5 independent 25x25 SPD systems plus
// a 25x25 Schur complement S = sum_w H_w^{-1} for the equality multipliers.
// Thread (w = tid/25, r = tid%25) owns row r of H_w (flat element ff=r*5+w).
// ---------------------------------------------------------------------------
__global__ __launch_bounds__(128) void qp_solve(const float* __restrict__ Kpart,
                                                const int* __restrict__ labels,
                                                float* __restrict__ zout) {
  const int b   = blockIdx.x;
  const int tid = threadIdx.x;
  const int w   = tid / 25;
  const int r   = tid % 25;
  const int ff  = r * 5 + w;
  const bool act   = (tid < NTOT);
  const bool act25 = (tid < 25);

  __shared__ float Ksh[25][26];
  __shared__ float Wb[5][25][26];   // H_w^{-1} rows
  __shared__ float pb[2][5][26];    // double-buffered pivot-row broadcast
  __shared__ float zv[NTOT];
  __shared__ float rs[NTOT];
  __shared__ float yv[NTOT];
  __shared__ float nuv[25];
  __shared__ float tv[25];
  __shared__ float dn[25];
  __shared__ float red[128];
  __shared__ float scal[2];

  // K = sum of the two half partials
  for (int p = tid; p < 625; p += 128) {
    Ksh[p / 25][p % 25] =
        Kpart[(size_t)b * 625 + p] + Kpart[(size_t)(BB + b) * 625 + p];
  }

  float z_ = 0.f, s_ = 0.f, l_ = 0.f, e_ = 0.f, rp_ = 0.f;
  if (act) {
    int lab  = labels[b * 25 + r];
    float oh = (lab == w) ? 1.0f : 0.0f;
    e_ = -oh;
    z_ = 0.1f * oh - 1.0f;   // h - 1
    s_ = 1.0f;
    l_ = 1.0f;
    zv[ff] = z_;
  }
  if (act25) nuv[tid] = 0.0f;
  __syncthreads();

  float Hr[25];
  float Sr[25];

#pragma unroll 1
  for (int it = 0; it < MAXIT; ++it) {
    // ---- (1) Dls, mu ----
    float d_ = 0.f, sl = 0.f;
    if (act) { d_ = l_ / s_; sl = s_ * l_; }
    float mu = block_reduce_sum(sl, red, scal, tid) / 125.0f;

    // ---- (2) r_d, r_p, build H rows ----
    float rd_ = 0.f;
    if (act) {
      float gz = z_;  // identity part of G
#pragma unroll
      for (int j = 0; j < 25; ++j) gz += Ksh[r][j] * zv[j * 5 + w];
      rd_ = gz + e_ + l_ + nuv[r];
#pragma unroll
      for (int j = 0; j < 25; ++j) Hr[j] = Ksh[r][j];
      Hr[r] += 1.0f + d_;
    }
    if (act25) {
      float a = 0.f;
#pragma unroll
      for (int q = 0; q < 5; ++q) a += zv[tid * 5 + q];
      rp_ = a;
    }
    __syncthreads();

    // ---- (3) in-place Gauss-Jordan inversion of the 5 H_w (parallel) ----
#pragma unroll
    for (int k = 0; k < 25; ++k) {
      if (act && r == k) {
        float pvt = 1.0f / Hr[k];
        Hr[k] = 1.0f;
#pragma unroll
        for (int j = 0; j < 25; ++j) { Hr[j] *= pvt; pb[k & 1][w][j] = Hr[j]; }
      }
      __syncthreads();
      if (act && r != k) {
        float f0 = Hr[k];
        Hr[k] = 0.0f;
#pragma unroll
        for (int j = 0; j < 25; ++j) Hr[j] = fmaf(-f0, pb[k & 1][w][j], Hr[j]);
      }
    }
    // Hr now = row r of W_w = H_w^{-1}
    if (act) {
#pragma unroll
      for (int j = 0; j < 25; ++j) Wb[w][r][j] = Hr[j];
      rs[ff] = l_ - rd_;  // predictor rhs1 = -r_d + lam
    }
    __syncthreads();

    // ---- (4) S = sum_w W_w ; predictor y = W rhs ----
    if (act25) {
#pragma unroll
      for (int j = 0; j < 25; ++j)
        Sr[j] = Wb[0][tid][j] + Wb[1][tid][j] + Wb[2][tid][j] +
                Wb[3][tid][j] + Wb[4][tid][j];
    }
    if (act) {
      float y = 0.f;
#pragma unroll
      for (int j = 0; j < 25; ++j) y = fmaf(Hr[j], rs[j * 5 + w], y);
      yv[ff] = y;
    }

    // ---- (5) invert S (25 threads) ----
#pragma unroll
    for (int k = 0; k < 25; ++k) {
      if (tid == k) {
        float pvt = 1.0f / Sr[k];
        Sr[k] = 1.0f;
#pragma unroll
        for (int j = 0; j < 25; ++j) { Sr[j] *= pvt; pb[k & 1][0][j] = Sr[j]; }
      }
      __syncthreads();
      if (act25 && tid != k) {
        float f0 = Sr[k];
        Sr[k] = 0.0f;
#pragma unroll
        for (int j = 0; j < 25; ++j) Sr[j] = fmaf(-f0, pb[k & 1][0][j], Sr[j]);
      }
    }

    // ---- (6) predictor dnu: S dnu = sum_w y_w + r_p ----
    if (act25) {
      float a = rp_;
#pragma unroll
      for (int q = 0; q < 5; ++q) a += yv[tid * 5 + q];
      tv[tid] = a;
    }
    __syncthreads();
    if (act25) {
      float a = 0.f;
#pragma unroll
      for (int j = 0; j < 25; ++j) a = fmaf(Sr[j], tv[j], a);
      dn[tid] = a;
    }
    __syncthreads();

    // ---- (7) predictor direction + alpha_aff ----
    float cand = 1.0f;
    float dza = 0.f, dsa = 0.f, dla = 0.f;
    if (act) {
      float wd = 0.f;
#pragma unroll
      for (int j = 0; j < 25; ++j) wd = fmaf(Hr[j], dn[j], wd);
      dza = yv[ff] - wd;
      dsa = -dza;
      dla = d_ * dza - l_;
      if (dsa < 0.f) cand = fminf(cand, -s_ / dsa);
      if (dla < 0.f) cand = fminf(cand, -l_ / dla);
    }
    float a_aff = block_reduce_min(cand, red, scal, tid);

    // ---- (8) mu_aff, sigma ----
    float pr = 0.f;
    if (act) pr = (s_ + a_aff * dsa) * (l_ + a_aff * dla);
    float mu_aff = block_reduce_sum(pr, red, scal, tid) / 125.0f;
    float rt = mu_aff / mu;
    float sig_mu = rt * rt * rt * mu;

    // ---- (9) corrector rhs ----
    float rc_ = 0.f;
    if (act) {
      rc_ = sig_mu - dsa * dla;
      rs[ff] = l_ - rd_ - rc_ / s_;
    }
    __syncthreads();

    // ---- (10) corrector y ----
    if (act) {
      float y = 0.f;
#pragma unroll
      for (int j = 0; j < 25; ++j) y = fmaf(Hr[j], rs[j * 5 + w], y);
      yv[ff] = y;
    }
    __syncthreads();

    // ---- (11) corrector dnu ----
    if (act25) {
      float a = rp_;
#pragma unroll
      for (int q = 0; q < 5; ++q) a += yv[tid * 5 + q];
      tv[tid] = a;
    }
    __syncthreads();
    if (act25) {
      float a = 0.f;
#pragma unroll
      for (int j = 0; j < 25; ++j) a = fmaf(Sr[j], tv[j], a);
      dn[tid] = a;
    }
    __syncthreads();

    // ---- (12) corrector direction + alpha ----
    cand = 1.0f;
    float dz2 = 0.f, ds2 = 0.f, dl2 = 0.f;
    if (act) {
      float wd = 0.f;
#pragma unroll
      for (int j = 0; j < 25; ++j) wd = fmaf(Hr[j], dn[j], wd);
      dz2 = yv[ff] - wd;
      ds2 = -dz2;
      dl2 = rc_ / s_ - l_ + d_ * dz2;
      if (ds2 < 0.f) cand = fminf(cand, -s_ / ds2);
      if (dl2 < 0.f) cand = fminf(cand, -l_ / dl2);
    }
    float a = 0.995f * block_reduce_min(cand, red, scal, tid);

    // ---- (13) update ----
    if (act) {
      z_ += a * dz2;
      s_ += a * ds2;
      l_ += a * dl2;
      zv[ff] = z_;
    }
    if (act25) nuv[tid] += a * dn[tid];
    __syncthreads();
  }

  if (act) zout[(size_t)b * NTOT + ff] = z_;
}

// ---------------------------------------------------------------------------
// Kernel C: ws[w][d] = sum_s z[s,w] * support[s][d]  (LDS), then
// logits[b][q][w] = scale * dot(query[b][q], ws[w])
// ---------------------------------------------------------------------------
__global__ __launch_bounds__(256) void k_logits(const float* __restrict__ sup,
                                                const float* __restrict__ query,
                                                const float* __restrict__ scale,
                                                const float* __restrict__ zsol,
                                                float* __restrict__ out) {
  const int b   = blockIdx.x;
  const int hq  = blockIdx.y;
  const int tid = threadIdx.x;

  __shared__ float wsb[5][2564];
  __shared__ float zsh[128];

  if (tid < NTOT) zsh[tid] = zsol[(size_t)b * NTOT + tid];
  __syncthreads();

  const float* Sb = sup + (size_t)b * NSUP * DIM;
  for (int d4 = tid; d4 < 640; d4 += 256) {
    float4 a0 = {0, 0, 0, 0}, a1 = {0, 0, 0, 0}, a2 = {0, 0, 0, 0},
           a3 = {0, 0, 0, 0}, a4 = {0, 0, 0, 0};
#pragma unroll
    for (int s = 0; s < 25; ++s) {
      float4 v = *(const float4*)(Sb + s * DIM + 4 * d4);
      float z0 = zsh[s * 5 + 0], z1 = zsh[s * 5 + 1], z2 = zsh[s * 5 + 2],
            z3 = zsh[s * 5 + 3], z4 = zsh[s * 5 + 4];
      FMA4(a0, z0, v);
      FMA4(a1, z1, v);
      FMA4(a2, z2, v);
      FMA4(a3, z3, v);
      FMA4(a4, z4, v);
    }
    *(float4*)&wsb[0][4 * d4] = a0;
    *(float4*)&wsb[1][4 * d4] = a1;
    *(float4*)&wsb[2][4 * d4] = a2;
    *(float4*)&wsb[3][4 * d4] = a3;
    *(float4*)&wsb[4][4 * d4] = a4;
  }
  __syncthreads();

  const float sc = scale[0];
  const int wv = tid >> 6, ln = tid & 63;
  const int q0 = hq * 38;
  const int q1 = (hq == 0) ? 38 : 75;

  for (int q = q0 + wv; q < q1; q += 4) {
    const float* Q = query + ((size_t)b * NQ + q) * DIM;
    float a0 = 0.f, a1 = 0.f, a2 = 0.f, a3 = 0.f, a4 = 0.f;
#pragma unroll
    for (int c = 0; c < 10; ++c) {
      int d4 = (c * 64 + ln) * 4;
      float4 qv = *(const float4*)(Q + d4);
      float4 w0 = *(const float4*)&wsb[0][d4];
      float4 w1 = *(const float4*)&wsb[1][d4];
      float4 w2 = *(const float4*)&wsb[2][d4];
      float4 w3 = *(const float4*)&wsb[3][d4];
      float4 w4 = *(const float4*)&wsb[4][d4];
      DOT4(a0, qv, w0);
      DOT4(a1, qv, w1);
      DOT4(a2, qv, w2);
      DOT4(a3, qv, w3);
      DOT4(a4, qv, w4);
    }
#pragma unroll
    for (int off = 32; off; off >>= 1) {
      a0 += __shfl_xor(a0, off);
      a1 += __shfl_xor(a1, off);
      a2 += __shfl_xor(a2, off);
      a3 += __shfl_xor(a3, off);
      a4 += __shfl_xor(a4, off);
    }
    if (ln == 0) {
      float* O = out + ((size_t)b * NQ + q) * NWAY;
      O[0] = sc * a0;
      O[1] = sc * a1;
      O[2] = sc * a2;
      O[3] = sc * a3;
      O[4] = sc * a4;
    }
  }
}

// ---------------------------------------------------------------------------
extern "C" void kernel_launch(void* const* d_in, const int* in_sizes, int n_in,
                              void* d_out, int out_size, void* d_ws, size_t ws_size,
                              hipStream_t stream) {
  (void)in_sizes; (void)n_in; (void)out_size; (void)ws_size;
  const float* query   = (const float*)d_in[0];
  const float* support = (const float*)d_in[1];
  const float* scale   = (const float*)d_in[2];
  const int*   labels  = (const int*)d_in[3];
  float* out = (float*)d_out;

  float* Kpart = (float*)d_ws;                 // [2][B][625]
  float* zsol  = Kpart + 2 * BB * 625;         // [B][125]

  dim3 gA(BB, 2);
  k_gram<<<gA, 256, 0, stream>>>(support, Kpart);

  qp_solve<<<dim3(BB), 128, 0, stream>>>(Kpart, labels, zsol);

  dim3 gC(BB, 2);
  k_logits<<<gC, 256, 0, stream>>>(support, query, scale, zsol, out);
}

// Round 2
// 566.839 us; speedup vs baseline: 1.1032x; 1.1032x over previous
//
#include <hip/hip_runtime.h>

constexpr int BB   = 128;   // batch
constexpr int NSUP = 25;    // support samples
constexpr int NWAY = 5;
constexpr int NTOT = 125;   // NSUP*NWAY
constexpr int NQ   = 75;
constexpr int DIM  = 2560;
constexpr int MAXIT = 15;

#define FMA4(acc, zz, v)                     \
  acc.x = fmaf(zz, v.x, acc.x);              \
  acc.y = fmaf(zz, v.y, acc.y);              \
  acc.z = fmaf(zz, v.z, acc.z);              \
  acc.w = fmaf(zz, v.w, acc.w)

#define DOT4(a, u, vv) a += u.x*vv.x + u.y*vv.y + u.z*vv.z + u.w*vv.w

// ---------------------------------------------------------------------------
// helpers
// ---------------------------------------------------------------------------
__device__ __forceinline__ float rlane(float v, int sl) {
  return __uint_as_float(__builtin_amdgcn_readlane(__float_as_uint(v), (unsigned)sl));
}

__device__ __forceinline__ float frcp(float x) {
#if __has_builtin(__builtin_amdgcn_rcpf)
  return __builtin_amdgcn_rcpf(x);   // v_rcp_f32, ~1 ulp — fine inside IPM
#else
  return 1.0f / x;
#endif
}

__device__ __forceinline__ float bfly_sum(float v) {
#pragma unroll
  for (int m = 32; m; m >>= 1) v += __shfl_xor(v, m);
  return v;
}
__device__ __forceinline__ float bfly_min(float v) {
#pragma unroll
  for (int m = 32; m; m >>= 1) v = fminf(v, __shfl_xor(v, m));
  return v;
}

// In-place Gauss-Jordan inverse of a 25x25 held column-per-lane:
// lane (h*32 + j), j<25, holds column j of matrix (h-half's matrix) in R[0..24].
// Pivot factors broadcast via v_readlane (sgpr feeds v_fma directly) — no LDS,
// no barriers. Lanes j>=25 compute garbage that is never sourced.
__device__ __forceinline__ void gj25_pair(float (&R)[25], int h, int j) {
#pragma unroll
  for (int k = 0; k < 25; ++k) {
    float pA = rlane(R[k], k);
    float pB = rlane(R[k], 32 + k);
    float pinv = frcp(h ? pB : pA);
    bool piv = (j == k);
    float ph = piv ? pinv : R[k] * pinv;
#pragma unroll
    for (int i = 0; i < 25; ++i) {
      if (i == k) continue;
      float fA = rlane(R[i], k);
      float fB = rlane(R[i], 32 + k);
      float f = h ? fB : fA;
      float base = piv ? 0.0f : R[i];
      R[i] = fmaf(-f, ph, base);
    }
    R[k] = ph;
  }
}

// ---------------------------------------------------------------------------
// Kernel A: K[b] = support[b] @ support[b]^T, split over 2 d-halves. (unchanged)
// ---------------------------------------------------------------------------
__global__ __launch_bounds__(256) void k_gram(const float* __restrict__ sup,
                                              float* __restrict__ Kpart) {
  const int b    = blockIdx.x;
  const int half = blockIdx.y;
  const int tid  = threadIdx.x;
  const int wv   = tid >> 6;
  const int ln   = tid & 63;

  __shared__ float tile[28][260];
  __shared__ float accb[4][49][16];

  for (int c = tid; c < 3 * 260; c += 256) tile[25 + c / 260][c % 260] = 0.0f;

  const float* S = sup + (size_t)b * NSUP * DIM + half * 1280;

  float acc[4][4];
#pragma unroll
  for (int x = 0; x < 4; ++x)
#pragma unroll
    for (int y = 0; y < 4; ++y) acc[x][y] = 0.0f;

  const int ti = ln / 7, tj = ln % 7;
  const int i0 = 4 * ti, j0 = 4 * tj;

  for (int ch = 0; ch < 5; ++ch) {
    __syncthreads();
    for (int q = tid; q < 1600; q += 256) {
      int rr = q >> 6, c4 = q & 63;
      float4 v = *(const float4*)(S + rr * DIM + ch * 256 + 4 * c4);
      *(float4*)&tile[rr][4 * c4] = v;
    }
    __syncthreads();
    if (ln < 49) {
#pragma unroll
      for (int c = 0; c < 16; ++c) {
        const int d4 = (wv * 16 + c) * 4;
        float4 av[4], bv[4];
#pragma unroll
        for (int x = 0; x < 4; ++x) av[x] = *(const float4*)&tile[i0 + x][d4];
#pragma unroll
        for (int y = 0; y < 4; ++y) bv[y] = *(const float4*)&tile[j0 + y][d4];
#pragma unroll
        for (int x = 0; x < 4; ++x)
#pragma unroll
          for (int y = 0; y < 4; ++y) {
            acc[x][y] += av[x].x * bv[y].x + av[x].y * bv[y].y +
                         av[x].z * bv[y].z + av[x].w * bv[y].w;
          }
      }
    }
  }

  if (ln < 49) {
#pragma unroll
    for (int x = 0; x < 4; ++x)
#pragma unroll
      for (int y = 0; y < 4; ++y) accb[wv][ln][x * 4 + y] = acc[x][y];
  }
  __syncthreads();

  for (int p = tid; p < 625; p += 256) {
    int i = p / 25, jx = p % 25;
    int lx = (i / 4) * 7 + (jx / 4);
    int sx = (i % 4) * 4 + (jx % 4);
    float v = accb[0][lx][sx] + accb[1][lx][sx] + accb[2][lx][sx] + accb[3][lx][sx];
    Kpart[((size_t)half * BB + b) * 625 + p] = v;
  }
}

// ---------------------------------------------------------------------------
// Kernel B: Mehrotra IPM, one block (192 threads = 3 waves) per batch element.
// Wave q inverts matrices {2q, 2q+1} (wave 2: m4 duplicated on both halves)
// with the barrier-free column/readlane Gauss-Jordan. 7 barriers per iter.
// ---------------------------------------------------------------------------
__global__ __launch_bounds__(192) void qp_solve2(const float* __restrict__ Kpart,
                                                 const int* __restrict__ labels,
                                                 float* __restrict__ zout) {
  const int b   = blockIdx.x;
  const int tid = threadIdx.x;
  const int wq  = tid >> 6;          // wave 0..2
  const int l   = tid & 63;
  const int h   = l >> 5;
  const int j   = l & 31;
  const bool act = (j < 25);
  const int jc  = act ? j : 0;
  const int matW = (wq == 2) ? 4 : 2 * wq + h;     // this lane's matrix
  const bool cnt = act && !(wq == 2 && h == 1);    // unique (w, sample) owner

  __shared__ float Klds[25][26];
  __shared__ float Wlds[5][25][26];   // H_w^{-1}, row-major
  __shared__ float SL[25][26];        // S^{-1}, row-major
  __shared__ float Vb[5][26];         // per-matrix matvec results
  __shared__ float Zl[5][26];         // z, per (way, sample)
  __shared__ float NUl[26];
  __shared__ float MU[4], AA[4], PP[4], CC[4];

  for (int p = tid; p < 625; p += 192)
    Klds[p / 25][p % 25] =
        Kpart[(size_t)b * 625 + p] + Kpart[(size_t)(BB + b) * 625 + p];

  // state for (matW, sample jc)
  int lab = labels[b * 25 + jc];
  float oh = (lab == matW) ? 1.0f : 0.0f;
  float e_ = -oh;
  float z_ = 0.1f * oh - 1.0f;   // h - 1
  float s_ = 1.0f, lm_ = 1.0f;

  if (wq == 0 && h == 0 && act) NUl[jc] = 0.0f;
  if (act) Zl[matW][jc] = z_;
  {
    float sl = cnt ? s_ * lm_ : 0.0f;
    sl = bfly_sum(sl);
    if (l == 0) MU[wq] = sl;
  }
  __syncthreads();

  float Kc[25];   // K column jc (K symmetric -> also row jc)
#pragma unroll
  for (int i = 0; i < 25; ++i) Kc[i] = Klds[i][jc];

  float R[25];

#pragma unroll 1
  for (int it = 0; it < MAXIT; ++it) {
    // ---- residuals, rhs ----
    float mu = (MU[0] + MU[1] + MU[2]) * (1.0f / 125.0f);
    float rp = Zl[0][jc] + Zl[1][jc] + Zl[2][jc] + Zl[3][jc] + Zl[4][jc];
    float nu = NUl[jc];
    float d_ = lm_ / s_;
    float kz = 0.0f;
#pragma unroll
    for (int i = 0; i < 25; ++i) {
      float zA = rlane(z_, i), zB = rlane(z_, 32 + i);
      kz = fmaf(Kc[i], h ? zB : zA, kz);
    }
    float rd = kz + z_ + e_ + lm_ + nu;
    float rhs1 = lm_ - rd;                   // -r_d + lam

    // ---- H = K + I + diag(lam/s); invert (pair, barrier-free) ----
#pragma unroll
    for (int i = 0; i < 25; ++i) R[i] = Kc[i] + ((j == i) ? (1.0f + d_) : 0.0f);
    gj25_pair(R, h, j);
    if (act) {
#pragma unroll
      for (int i = 0; i < 25; ++i) Wlds[matW][i][jc] = R[i];
    }
    __syncthreads();                          // B2: W published

    // ---- v = W_w rhs1_w (row-style) ; S = sum_w W_w ; invert S ----
    const float* Wrow = &Wlds[matW][jc][0];
    float v1 = 0.0f;
#pragma unroll
    for (int m = 0; m < 25; ++m) {
      float fA = rlane(rhs1, m), fB = rlane(rhs1, 32 + m);
      v1 = fmaf(Wrow[m], h ? fB : fA, v1);
    }
    if (act) Vb[matW][jc] = v1;
#pragma unroll
    for (int i = 0; i < 25; ++i)
      R[i] = Wlds[0][i][jc] + Wlds[1][i][jc] + Wlds[2][i][jc] +
             Wlds[3][i][jc] + Wlds[4][i][jc];
    gj25_pair(R, h, j);                       // all waves redundantly (dup halves)
    if (act && h == 0 && wq == 0) {
#pragma unroll
      for (int i = 0; i < 25; ++i) SL[i][jc] = R[i];
    }
    __syncthreads();                          // B3: Sinv + Vb ready

    // ---- predictor: S dnu = sum v + r_p ; dz = W(rhs1 - dnu) ----
    float u = Vb[0][jc] + Vb[1][jc] + Vb[2][jc] + Vb[3][jc] + Vb[4][jc];
    float t = u + rp;
    const float* Srow = &SL[jc][0];
    float dn1 = 0.0f;
#pragma unroll
    for (int m = 0; m < 25; ++m) dn1 = fmaf(Srow[m], rlane(t, m), dn1);
    float r2 = rhs1 - dn1;
    float dz1 = 0.0f;
#pragma unroll
    for (int m = 0; m < 25; ++m) {
      float fA = rlane(r2, m), fB = rlane(r2, 32 + m);
      dz1 = fmaf(Wrow[m], h ? fB : fA, dz1);
    }
    float ds1 = -dz1;
    float dl1 = fmaf(d_, dz1, -lm_);
    float cand = 1.0f;
    if (act) {
      if (ds1 < 0.0f) cand = fminf(cand, -s_ / ds1);
      if (dl1 < 0.0f) cand = fminf(cand, -lm_ / dl1);
    }
    cand = bfly_min(cand);
    if (l == 0) AA[wq] = cand;
    __syncthreads();                          // B4
    float a_aff = fminf(AA[0], fminf(AA[1], AA[2]));
    float pr = cnt ? (s_ + a_aff * ds1) * (lm_ + a_aff * dl1) : 0.0f;
    pr = bfly_sum(pr);
    if (l == 0) PP[wq] = pr;
    __syncthreads();                          // B5
    float mu_aff = (PP[0] + PP[1] + PP[2]) * (1.0f / 125.0f);
    float rt = mu_aff / mu;
    float sg = rt * rt * rt * mu;

    // ---- corrector ----
    float rc = sg - ds1 * dl1;
    float rhsc = lm_ - rd - rc / s_;
    float v2 = 0.0f;
#pragma unroll
    for (int m = 0; m < 25; ++m) {
      float fA = rlane(rhsc, m), fB = rlane(rhsc, 32 + m);
      v2 = fmaf(Wrow[m], h ? fB : fA, v2);
    }
    if (act) Vb[matW][jc] = v2;               // Vb consumed before B4 -> safe
    __syncthreads();                          // B6
    float u2 = Vb[0][jc] + Vb[1][jc] + Vb[2][jc] + Vb[3][jc] + Vb[4][jc];
    float t2 = u2 + rp;
    float dn2 = 0.0f;
#pragma unroll
    for (int m = 0; m < 25; ++m) dn2 = fmaf(Srow[m], rlane(t2, m), dn2);
    float r2c = rhsc - dn2;
    float dz2 = 0.0f;
#pragma unroll
    for (int m = 0; m < 25; ++m) {
      float fA = rlane(r2c, m), fB = rlane(r2c, 32 + m);
      dz2 = fmaf(Wrow[m], h ? fB : fA, dz2);
    }
    float ds2 = -dz2;
    float dl2 = rc / s_ - lm_ + d_ * dz2;
    float c2 = 1.0f;
    if (act) {
      if (ds2 < 0.0f) c2 = fminf(c2, -s_ / ds2);
      if (dl2 < 0.0f) c2 = fminf(c2, -lm_ / dl2);
    }
    c2 = bfly_min(c2);
    if (l == 0) CC[wq] = c2;
    __syncthreads();                          // B7
    float a = 0.995f * fminf(CC[0], fminf(CC[1], CC[2]));

    // ---- update ----
    z_  = fmaf(a, dz2, z_);
    s_  = fmaf(a, ds2, s_);
    lm_ = fmaf(a, dl2, lm_);
    if (wq == 0 && h == 0 && act) NUl[jc] = nu + a * dn2;
    if (act) Zl[matW][jc] = z_;
    {
      float sl = cnt ? s_ * lm_ : 0.0f;
      sl = bfly_sum(sl);
      if (l == 0) MU[wq] = sl;
    }
    __syncthreads();                          // B8 (= B1 of next iter)
  }

  if (cnt) zout[(size_t)b * NTOT + jc * 5 + matW] = z_;
}

// ---------------------------------------------------------------------------
// Kernel C1: ws[b][w][d] = sum_s z[s,w] * support[s][d]  (once per batch)
// ---------------------------------------------------------------------------
__global__ __launch_bounds__(256) void k_ws(const float* __restrict__ sup,
                                            const float* __restrict__ zsol,
                                            float* __restrict__ ws) {
  const int b   = blockIdx.x;
  const int tid = threadIdx.x;
  __shared__ float zsh[NTOT];
  if (tid < NTOT) zsh[tid] = zsol[(size_t)b * NTOT + tid];
  __syncthreads();

  const float* Sb = sup + (size_t)b * NSUP * DIM;
  for (int d4 = tid; d4 < 640; d4 += 256) {
    float4 a0 = {0,0,0,0}, a1 = {0,0,0,0}, a2 = {0,0,0,0}, a3 = {0,0,0,0}, a4 = {0,0,0,0};
#pragma unroll
    for (int s = 0; s < 25; ++s) {
      float4 v = *(const float4*)(Sb + s * DIM + 4 * d4);
      float z0 = zsh[s*5+0], z1 = zsh[s*5+1], z2 = zsh[s*5+2], z3 = zsh[s*5+3], z4 = zsh[s*5+4];
      FMA4(a0, z0, v); FMA4(a1, z1, v); FMA4(a2, z2, v); FMA4(a3, z3, v); FMA4(a4, z4, v);
    }
    float* W = ws + (size_t)b * NWAY * DIM;
    *(float4*)(W + 0*DIM + 4*d4) = a0;
    *(float4*)(W + 1*DIM + 4*d4) = a1;
    *(float4*)(W + 2*DIM + 4*d4) = a2;
    *(float4*)(W + 3*DIM + 4*d4) = a3;
    *(float4*)(W + 4*DIM + 4*d4) = a4;
  }
}

// ---------------------------------------------------------------------------
// Kernel C2: logits[b][q][w] = scale * dot(query[b][q], ws[b][w]), 15 q/block
// ---------------------------------------------------------------------------
__global__ __launch_bounds__(256) void k_logits2(const float* __restrict__ query,
                                                 const float* __restrict__ scale,
                                                 const float* __restrict__ ws,
                                                 float* __restrict__ out) {
  const int b   = blockIdx.x;
  const int qt  = blockIdx.y;
  const int tid = threadIdx.x;
  const int wv  = tid >> 6, ln = tid & 63;

  __shared__ float wsb[5][2564];
  for (int p = tid; p < 3200; p += 256) {
    int w = p / 640, c = p % 640;
    *(float4*)&wsb[w][4 * c] = *(const float4*)(ws + ((size_t)b * NWAY + w) * DIM + 4 * c);
  }
  __syncthreads();

  const float sc = scale[0];
  const int q0 = qt * 15, q1 = q0 + 15;
  for (int q = q0 + wv; q < q1; q += 4) {
    const float* Q = query + ((size_t)b * NQ + q) * DIM;
    float a0 = 0.f, a1 = 0.f, a2 = 0.f, a3 = 0.f, a4 = 0.f;
#pragma unroll
    for (int c = 0; c < 10; ++c) {
      int d4 = (c * 64 + ln) * 4;
      float4 qv = *(const float4*)(Q + d4);
      float4 w0 = *(const float4*)&wsb[0][d4];
      float4 w1 = *(const float4*)&wsb[1][d4];
      float4 w2 = *(const float4*)&wsb[2][d4];
      float4 w3 = *(const float4*)&wsb[3][d4];
      float4 w4 = *(const float4*)&wsb[4][d4];
      DOT4(a0, qv, w0); DOT4(a1, qv, w1); DOT4(a2, qv, w2); DOT4(a3, qv, w3); DOT4(a4, qv, w4);
    }
#pragma unroll
    for (int off = 32; off; off >>= 1) {
      a0 += __shfl_xor(a0, off); a1 += __shfl_xor(a1, off); a2 += __shfl_xor(a2, off);
      a3 += __shfl_xor(a3, off); a4 += __shfl_xor(a4, off);
    }
    if (ln == 0) {
      float* O = out + ((size_t)b * NQ + q) * NWAY;
      O[0] = sc*a0; O[1] = sc*a1; O[2] = sc*a2; O[3] = sc*a3; O[4] = sc*a4;
    }
  }
}

// ---------------------------------------------------------------------------
// Fallback fused logits (if workspace too small for ws buffer)
// ---------------------------------------------------------------------------
__global__ __launch_bounds__(256) void k_logits(const float* __restrict__ sup,
                                                const float* __restrict__ query,
                                                const float* __restrict__ scale,
                                                const float* __restrict__ zsol,
                                                float* __restrict__ out) {
  const int b   = blockIdx.x;
  const int hq  = blockIdx.y;
  const int tid = threadIdx.x;

  __shared__ float wsb[5][2564];
  __shared__ float zsh[128];

  if (tid < NTOT) zsh[tid] = zsol[(size_t)b * NTOT + tid];
  __syncthreads();

  const float* Sb = sup + (size_t)b * NSUP * DIM;
  for (int d4 = tid; d4 < 640; d4 += 256) {
    float4 a0 = {0,0,0,0}, a1 = {0,0,0,0}, a2 = {0,0,0,0}, a3 = {0,0,0,0}, a4 = {0,0,0,0};
#pragma unroll
    for (int s = 0; s < 25; ++s) {
      float4 v = *(const float4*)(Sb + s * DIM + 4 * d4);
      float z0 = zsh[s*5+0], z1 = zsh[s*5+1], z2 = zsh[s*5+2], z3 = zsh[s*5+3], z4 = zsh[s*5+4];
      FMA4(a0, z0, v); FMA4(a1, z1, v); FMA4(a2, z2, v); FMA4(a3, z3, v); FMA4(a4, z4, v);
    }
    *(float4*)&wsb[0][4*d4] = a0; *(float4*)&wsb[1][4*d4] = a1; *(float4*)&wsb[2][4*d4] = a2;
    *(float4*)&wsb[3][4*d4] = a3; *(float4*)&wsb[4][4*d4] = a4;
  }
  __syncthreads();

  const float sc = scale[0];
  const int wv = tid >> 6, ln = tid & 63;
  const int q0 = hq * 38;
  const int q1 = (hq == 0) ? 38 : 75;

  for (int q = q0 + wv; q < q1; q += 4) {
    const float* Q = query + ((size_t)b * NQ + q) * DIM;
    float a0 = 0.f, a1 = 0.f, a2 = 0.f, a3 = 0.f, a4 = 0.f;
#pragma unroll
    for (int c = 0; c < 10; ++c) {
      int d4 = (c * 64 + ln) * 4;
      float4 qv = *(const float4*)(Q + d4);
      float4 w0 = *(const float4*)&wsb[0][d4];
      float4 w1 = *(const float4*)&wsb[1][d4];
      float4 w2 = *(const float4*)&wsb[2][d4];
      float4 w3 = *(const float4*)&wsb[3][d4];
      float4 w4 = *(const float4*)&wsb[4][d4];
      DOT4(a0, qv, w0); DOT4(a1, qv, w1); DOT4(a2, qv, w2); DOT4(a3, qv, w3); DOT4(a4, qv, w4);
    }
#pragma unroll
    for (int off = 32; off; off >>= 1) {
      a0 += __shfl_xor(a0, off); a1 += __shfl_xor(a1, off); a2 += __shfl_xor(a2, off);
      a3 += __shfl_xor(a3, off); a4 += __shfl_xor(a4, off);
    }
    if (ln == 0) {
      float* O = out + ((size_t)b * NQ + q) * NWAY;
      O[0] = sc*a0; O[1] = sc*a1; O[2] = sc*a2; O[3] = sc*a3; O[4] = sc*a4;
    }
  }
}

// ---------------------------------------------------------------------------
extern "C" void kernel_launch(void* const* d_in, const int* in_sizes, int n_in,
                              void* d_out, int out_size, void* d_ws, size_t ws_size,
                              hipStream_t stream) {
  (void)in_sizes; (void)n_in; (void)out_size;
  const float* query   = (const float*)d_in[0];
  const float* support = (const float*)d_in[1];
  const float* scale   = (const float*)d_in[2];
  const int*   labels  = (const int*)d_in[3];
  float* out = (float*)d_out;

  float* Kpart = (float*)d_ws;                       // [2][B][625]
  float* zsol  = Kpart + 2 * BB * 625;               // [B][125]
  float* wsbuf = zsol + BB * NTOT;                   // [B][5][2560]
  const size_t need = (size_t)(2*BB*625 + BB*NTOT + BB*NWAY*DIM) * 4;

  dim3 gA(BB, 2);
  k_gram<<<gA, 256, 0, stream>>>(support, Kpart);

  qp_solve2<<<dim3(BB), 192, 0, stream>>>(Kpart, labels, zsol);

  if (ws_size >= need) {
    k_ws<<<dim3(BB), 256, 0, stream>>>(support, zsol, wsbuf);
    k_logits2<<<dim3(BB, 5), 256, 0, stream>>>(query, scale, wsbuf, out);
  } else {
    k_logits<<<dim3(BB, 2), 256, 0, stream>>>(support, query, scale, zsol, out);
  }
}

// Round 3
// 557.064 us; speedup vs baseline: 1.1226x; 1.0175x over previous
//
#include <hip/hip_runtime.h>
#include <utility>

constexpr int BB   = 128;   // batch
constexpr int NSUP = 25;    // support samples
constexpr int NWAY = 5;
constexpr int NTOT = 125;   // NSUP*NWAY
constexpr int NQ   = 75;
constexpr int DIM  = 2560;
constexpr int MAXIT = 15;

#define FMA4(acc, zz, v)                     \
  acc.x = fmaf(zz, v.x, acc.x);              \
  acc.y = fmaf(zz, v.y, acc.y);              \
  acc.z = fmaf(zz, v.z, acc.z);              \
  acc.w = fmaf(zz, v.w, acc.w)

#define DOT4(a, u, vv) a += u.x*vv.x + u.y*vv.y + u.z*vv.z + u.w*vv.w

// ---------------------------------------------------------------------------
// helpers
// ---------------------------------------------------------------------------
__device__ __forceinline__ float frcp(float x) {
#if __has_builtin(__builtin_amdgcn_rcpf)
  return __builtin_amdgcn_rcpf(x);   // v_rcp_f32, ~1 ulp — fine inside IPM
#else
  return 1.0f / x;
#endif
}

// ds_swizzle broadcast of lane K within each 32-lane group (BitMode:
// src = ((l & 0) | K) ^ 0 = K). One LDS-pipe op replaces 2 readlanes + select.
template <int IMM>
__device__ __forceinline__ float swzb(float v) {
  return __uint_as_float(
      (unsigned)__builtin_amdgcn_ds_swizzle((int)__float_as_uint(v), IMM));
}
template <int K>
__device__ __forceinline__ float bcast32(float v) {
  return swzb<(K << 5)>(v);
}

__device__ __forceinline__ float bfly_sum(float v) {
#pragma unroll
  for (int m = 32; m; m >>= 1) v += __shfl_xor(v, m);
  return v;
}
__device__ __forceinline__ float bfly_min(float v) {
#pragma unroll
  for (int m = 32; m; m >>= 1) v = fminf(v, __shfl_xor(v, m));
  return v;
}

// In-place Gauss-Jordan inverse of a 25x25 held column-per-lane in each
// 32-lane half (lane h*32+j, j<25, holds column j). Pivot/factor broadcasts
// via ds_swizzle; no barriers, no readlanes, both halves fully vectorized.
template <int K>
__device__ __forceinline__ void gj_step(float (&R)[25], int j) {
  float pk   = bcast32<K>(R[K]);
  float pinv = frcp(pk);
  bool  piv  = (j == K);
  float ph   = piv ? pinv : R[K] * pinv;
#pragma unroll
  for (int i = 0; i < 25; ++i) {
    if (i == K) continue;
    float f    = bcast32<K>(R[i]);
    float base = piv ? 0.0f : R[i];
    R[i] = fmaf(-f, ph, base);
  }
  R[K] = ph;
}
template <int... Ks>
__device__ __forceinline__ void gj25_all(float (&R)[25], int j,
                                         std::integer_sequence<int, Ks...>) {
  (gj_step<Ks>(R, j), ...);
}
__device__ __forceinline__ void gj25(float (&R)[25], int j) {
  gj25_all(R, j, std::make_integer_sequence<int, 25>{});
}

// row (registers) dot broadcast(x): y = sum_m row[m] * x[lane m of my half]
template <int O, int... Ms>
__device__ __forceinline__ float mv_part(const float (&row)[25], float x,
                                         std::integer_sequence<int, Ms...>) {
  float acc = 0.0f;
  ((acc = fmaf(row[O + Ms], bcast32<O + Ms>(x), acc)), ...);
  return acc;
}
__device__ __forceinline__ float mv25(const float (&row)[25], float x) {
  return mv_part<0>(row, x, std::make_integer_sequence<int, 13>{}) +
         mv_part<13>(row, x, std::make_integer_sequence<int, 12>{});
}

// ---------------------------------------------------------------------------
// Kernel A: K[b] = support[b] @ support[b]^T, split over 2 d-halves.
// ---------------------------------------------------------------------------
__global__ __launch_bounds__(256) void k_gram(const float* __restrict__ sup,
                                              float* __restrict__ Kpart) {
  const int b    = blockIdx.x;
  const int half = blockIdx.y;
  const int tid  = threadIdx.x;
  const int wv   = tid >> 6;
  const int ln   = tid & 63;

  __shared__ float tile[28][260];
  __shared__ float accb[4][49][16];

  for (int c = tid; c < 3 * 260; c += 256) tile[25 + c / 260][c % 260] = 0.0f;

  const float* S = sup + (size_t)b * NSUP * DIM + half * 1280;

  float acc[4][4];
#pragma unroll
  for (int x = 0; x < 4; ++x)
#pragma unroll
    for (int y = 0; y < 4; ++y) acc[x][y] = 0.0f;

  const int ti = ln / 7, tj = ln % 7;
  const int i0 = 4 * ti, j0 = 4 * tj;

  for (int ch = 0; ch < 5; ++ch) {
    __syncthreads();
    for (int q = tid; q < 1600; q += 256) {
      int rr = q >> 6, c4 = q & 63;
      float4 v = *(const float4*)(S + rr * DIM + ch * 256 + 4 * c4);
      *(float4*)&tile[rr][4 * c4] = v;
    }
    __syncthreads();
    if (ln < 49) {
#pragma unroll
      for (int c = 0; c < 16; ++c) {
        const int d4 = (wv * 16 + c) * 4;
        float4 av[4], bv[4];
#pragma unroll
        for (int x = 0; x < 4; ++x) av[x] = *(const float4*)&tile[i0 + x][d4];
#pragma unroll
        for (int y = 0; y < 4; ++y) bv[y] = *(const float4*)&tile[j0 + y][d4];
#pragma unroll
        for (int x = 0; x < 4; ++x)
#pragma unroll
          for (int y = 0; y < 4; ++y) {
            acc[x][y] += av[x].x * bv[y].x + av[x].y * bv[y].y +
                         av[x].z * bv[y].z + av[x].w * bv[y].w;
          }
      }
    }
  }

  if (ln < 49) {
#pragma unroll
    for (int x = 0; x < 4; ++x)
#pragma unroll
      for (int y = 0; y < 4; ++y) accb[wv][ln][x * 4 + y] = acc[x][y];
  }
  __syncthreads();

  for (int p = tid; p < 625; p += 256) {
    int i = p / 25, jx = p % 25;
    int lx = (i / 4) * 7 + (jx / 4);
    int sx = (i % 4) * 4 + (jx % 4);
    float v = accb[0][lx][sx] + accb[1][lx][sx] + accb[2][lx][sx] + accb[3][lx][sx];
    Kpart[((size_t)half * BB + b) * 625 + p] = v;
  }
}

// ---------------------------------------------------------------------------
// Kernel B: Mehrotra IPM, one block (192 threads = 3 waves) per batch element.
// Wave q owns matrices {2q, 2q+1} in its two 32-lane halves (wave 2: m4
// duplicated). All broadcasts are ds_swizzle within halves; W/S rows cached
// in registers after one LDS transpose. 7 barriers per iteration.
// ---------------------------------------------------------------------------
__global__ __launch_bounds__(192) void qp_solve3(const float* __restrict__ Kpart,
                                                 const int* __restrict__ labels,
                                                 float* __restrict__ zout) {
  const int b   = blockIdx.x;
  const int tid = threadIdx.x;
  const int wq  = tid >> 6;          // wave 0..2
  const int l   = tid & 63;
  const int h   = l >> 5;
  const int j   = l & 31;
  const bool act = (j < 25);
  const int jc  = act ? j : 0;
  const int matW = (wq == 2) ? 4 : 2 * wq + h;
  const bool cnt = act && !(wq == 2 && h == 1);   // unique (sample, way) owner

  __shared__ float Klds[25][26];
  __shared__ float Wlds[5][25][26];   // H_w^{-1} (column-major write, row read)
  __shared__ float SL[25][26];        // S^{-1}
  __shared__ float Vb[5][28];
  __shared__ float Zl[5][28];
  __shared__ float NUl[28];
  __shared__ float MU[4], AA[4], PP[4], CC[4];

  for (int p = tid; p < 625; p += 192)
    Klds[p / 25][p % 25] =
        Kpart[(size_t)b * 625 + p] + Kpart[(size_t)(BB + b) * 625 + p];

  int lab = labels[b * 25 + jc];
  float oh = (lab == matW) ? 1.0f : 0.0f;
  float e_ = -oh;
  float z_ = 0.1f * oh - 1.0f;   // h - 1
  float s_ = 1.0f, lm_ = 1.0f;

  if (wq == 0 && h == 0 && act) NUl[jc] = 0.0f;
  if (cnt) Zl[matW][jc] = z_;
  {
    float sl = cnt ? s_ * lm_ : 0.0f;
    sl = bfly_sum(sl);
    if (l == 0) MU[wq] = sl;
  }
  __syncthreads();

  float Kc[25];   // K column jc (K symmetric -> also row jc)
#pragma unroll
  for (int i = 0; i < 25; ++i) Kc[i] = Klds[i][jc];

  float R[25], Wrow[25], Srow[25];

#pragma unroll 1
  for (int it = 0; it < MAXIT; ++it) {
    // ---- residuals ----
    float mu = (MU[0] + MU[1] + MU[2]) * (1.0f / 125.0f);
    float rp = Zl[0][jc] + Zl[1][jc] + Zl[2][jc] + Zl[3][jc] + Zl[4][jc];
    float nu = NUl[jc];
    float d_ = lm_ / s_;
    float kz = mv25(Kc, z_);
    float rd = kz + z_ + e_ + lm_ + nu;
    float rhs1 = lm_ - rd;                   // -r_d + lam

    // ---- H = K + I + diag(lam/s); invert (swizzle GJ, barrier-free) ----
#pragma unroll
    for (int i = 0; i < 25; ++i) R[i] = Kc[i] + ((j == i) ? (1.0f + d_) : 0.0f);
    gj25(R, j);
    if (cnt) {
#pragma unroll
      for (int i = 0; i < 25; ++i) Wlds[matW][i][jc] = R[i];
    }
    __syncthreads();                          // B_A: W published

    // W row into registers; predictor v1 = W rhs1
#pragma unroll
    for (int m = 0; m < 25; ++m) Wrow[m] = Wlds[matW][jc][m];
    float v1 = mv25(Wrow, rhs1);
    if (cnt) Vb[matW][jc] = v1;

    // S = sum_w W_w ; invert (wave 0 only — others would be redundant)
    if (wq == 0) {
#pragma unroll
      for (int i = 0; i < 25; ++i)
        R[i] = Wlds[0][i][jc] + Wlds[1][i][jc] + Wlds[2][i][jc] +
               Wlds[3][i][jc] + Wlds[4][i][jc];
      gj25(R, j);
      if (h == 0 && act) {
#pragma unroll
        for (int i = 0; i < 25; ++i) SL[i][jc] = R[i];
      }
    }
    __syncthreads();                          // B_B: Sinv + Vb ready
#pragma unroll
    for (int m = 0; m < 25; ++m) Srow[m] = SL[jc][m];

    // ---- predictor ----
    float u = Vb[0][jc] + Vb[1][jc] + Vb[2][jc] + Vb[3][jc] + Vb[4][jc];
    float t = u + rp;
    float dn1 = mv25(Srow, t);
    float r2 = rhs1 - dn1;
    float dz1 = mv25(Wrow, r2);
    float ds1 = -dz1;
    float dl1 = fmaf(d_, dz1, -lm_);
    float cand = 1.0f;
    if (act) {
      if (ds1 < 0.0f) cand = fminf(cand, -s_ / ds1);
      if (dl1 < 0.0f) cand = fminf(cand, -lm_ / dl1);
    }
    cand = bfly_min(cand);
    if (l == 0) AA[wq] = cand;
    __syncthreads();                          // B_C
    float a_aff = fminf(AA[0], fminf(AA[1], AA[2]));
    float pr = cnt ? (s_ + a_aff * ds1) * (lm_ + a_aff * dl1) : 0.0f;
    pr = bfly_sum(pr);
    if (l == 0) PP[wq] = pr;
    __syncthreads();                          // B_D
    float mu_aff = (PP[0] + PP[1] + PP[2]) * (1.0f / 125.0f);
    float rt = mu_aff / mu;
    float sg = rt * rt * rt * mu;

    // ---- corrector ----
    float rc = sg - ds1 * dl1;
    float rhsc = lm_ - rd - rc / s_;
    float v2 = mv25(Wrow, rhsc);
    if (cnt) Vb[matW][jc] = v2;
    __syncthreads();                          // B_E
    float u2 = Vb[0][jc] + Vb[1][jc] + Vb[2][jc] + Vb[3][jc] + Vb[4][jc];
    float t2 = u2 + rp;
    float dn2 = mv25(Srow, t2);
    float r2c = rhsc - dn2;
    float dz2 = mv25(Wrow, r2c);
    float ds2 = -dz2;
    float dl2 = rc / s_ - lm_ + d_ * dz2;
    float c2 = 1.0f;
    if (act) {
      if (ds2 < 0.0f) c2 = fminf(c2, -s_ / ds2);
      if (dl2 < 0.0f) c2 = fminf(c2, -lm_ / dl2);
    }
    c2 = bfly_min(c2);
    if (l == 0) CC[wq] = c2;
    __syncthreads();                          // B_F
    float a = 0.995f * fminf(CC[0], fminf(CC[1], CC[2]));

    // ---- update ----
    z_  = fmaf(a, dz2, z_);
    s_  = fmaf(a, ds2, s_);
    lm_ = fmaf(a, dl2, lm_);
    if (wq == 0 && h == 0 && act) NUl[jc] = nu + a * dn2;
    if (cnt) Zl[matW][jc] = z_;
    {
      float sl = cnt ? s_ * lm_ : 0.0f;
      sl = bfly_sum(sl);
      if (l == 0) MU[wq] = sl;
    }
    __syncthreads();                          // B_G (= top of next iter)
  }

  if (cnt) zout[(size_t)b * NTOT + jc * 5 + matW] = z_;
}

// ---------------------------------------------------------------------------
// Kernel C1: ws[b][w][d] = sum_s z[s,w] * support[s][d]
// ---------------------------------------------------------------------------
__global__ __launch_bounds__(256) void k_ws(const float* __restrict__ sup,
                                            const float* __restrict__ zsol,
                                            float* __restrict__ ws) {
  const int b   = blockIdx.x;
  const int tid = threadIdx.x;
  __shared__ float zsh[NTOT];
  if (tid < NTOT) zsh[tid] = zsol[(size_t)b * NTOT + tid];
  __syncthreads();

  const float* Sb = sup + (size_t)b * NSUP * DIM;
  for (int d4 = tid; d4 < 640; d4 += 256) {
    float4 a0 = {0,0,0,0}, a1 = {0,0,0,0}, a2 = {0,0,0,0}, a3 = {0,0,0,0}, a4 = {0,0,0,0};
#pragma unroll
    for (int s = 0; s < 25; ++s) {
      float4 v = *(const float4*)(Sb + s * DIM + 4 * d4);
      float z0 = zsh[s*5+0], z1 = zsh[s*5+1], z2 = zsh[s*5+2], z3 = zsh[s*5+3], z4 = zsh[s*5+4];
      FMA4(a0, z0, v); FMA4(a1, z1, v); FMA4(a2, z2, v); FMA4(a3, z3, v); FMA4(a4, z4, v);
    }
    float* W = ws + (size_t)b * NWAY * DIM;
    *(float4*)(W + 0*DIM + 4*d4) = a0;
    *(float4*)(W + 1*DIM + 4*d4) = a1;
    *(float4*)(W + 2*DIM + 4*d4) = a2;
    *(float4*)(W + 3*DIM + 4*d4) = a3;
    *(float4*)(W + 4*DIM + 4*d4) = a4;
  }
}

// ---------------------------------------------------------------------------
// Kernel C2: logits[b][q][w] = scale * dot(query[b][q], ws[b][w])
// ---------------------------------------------------------------------------
__global__ __launch_bounds__(256) void k_logits2(const float* __restrict__ query,
                                                 const float* __restrict__ scale,
                                                 const float* __restrict__ ws,
                                                 float* __restrict__ out) {
  const int b   = blockIdx.x;
  const int qt  = blockIdx.y;
  const int tid = threadIdx.x;
  const int wv  = tid >> 6, ln = tid & 63;

  __shared__ float wsb[5][2564];
  for (int p = tid; p < 3200; p += 256) {
    int w = p / 640, c = p % 640;
    *(float4*)&wsb[w][4 * c] = *(const float4*)(ws + ((size_t)b * NWAY + w) * DIM + 4 * c);
  }
  __syncthreads();

  const float sc = scale[0];
  const int q0 = qt * 15, q1 = q0 + 15;
  for (int q = q0 + wv; q < q1; q += 4) {
    const float* Q = query + ((size_t)b * NQ + q) * DIM;
    float a0 = 0.f, a1 = 0.f, a2 = 0.f, a3 = 0.f, a4 = 0.f;
#pragma unroll
    for (int c = 0; c < 10; ++c) {
      int d4 = (c * 64 + ln) * 4;
      float4 qv = *(const float4*)(Q + d4);
      float4 w0 = *(const float4*)&wsb[0][d4];
      float4 w1 = *(const float4*)&wsb[1][d4];
      float4 w2 = *(const float4*)&wsb[2][d4];
      float4 w3 = *(const float4*)&wsb[3][d4];
      float4 w4 = *(const float4*)&wsb[4][d4];
      DOT4(a0, qv, w0); DOT4(a1, qv, w1); DOT4(a2, qv, w2); DOT4(a3, qv, w3); DOT4(a4, qv, w4);
    }
#pragma unroll
    for (int off = 32; off; off >>= 1) {
      a0 += __shfl_xor(a0, off); a1 += __shfl_xor(a1, off); a2 += __shfl_xor(a2, off);
      a3 += __shfl_xor(a3, off); a4 += __shfl_xor(a4, off);
    }
    if (ln == 0) {
      float* O = out + ((size_t)b * NQ + q) * NWAY;
      O[0] = sc*a0; O[1] = sc*a1; O[2] = sc*a2; O[3] = sc*a3; O[4] = sc*a4;
    }
  }
}

// ---------------------------------------------------------------------------
// Fallback fused logits (if workspace too small for ws buffer)
// ---------------------------------------------------------------------------
__global__ __launch_bounds__(256) void k_logits(const float* __restrict__ sup,
                                                const float* __restrict__ query,
                                                const float* __restrict__ scale,
                                                const float* __restrict__ zsol,
                                                float* __restrict__ out) {
  const int b   = blockIdx.x;
  const int hq  = blockIdx.y;
  const int tid = threadIdx.x;

  __shared__ float wsb[5][2564];
  __shared__ float zsh[128];

  if (tid < NTOT) zsh[tid] = zsol[(size_t)b * NTOT + tid];
  __syncthreads();

  const float* Sb = sup + (size_t)b * NSUP * DIM;
  for (int d4 = tid; d4 < 640; d4 += 256) {
    float4 a0 = {0,0,0,0}, a1 = {0,0,0,0}, a2 = {0,0,0,0}, a3 = {0,0,0,0}, a4 = {0,0,0,0};
#pragma unroll
    for (int s = 0; s < 25; ++s) {
      float4 v = *(const float4*)(Sb + s * DIM + 4 * d4);
      float z0 = zsh[s*5+0], z1 = zsh[s*5+1], z2 = zsh[s*5+2], z3 = zsh[s*5+3], z4 = zsh[s*5+4];
      FMA4(a0, z0, v); FMA4(a1, z1, v); FMA4(a2, z2, v); FMA4(a3, z3, v); FMA4(a4, z4, v);
    }
    *(float4*)&wsb[0][4*d4] = a0; *(float4*)&wsb[1][4*d4] = a1; *(float4*)&wsb[2][4*d4] = a2;
    *(float4*)&wsb[3][4*d4] = a3; *(float4*)&wsb[4][4*d4] = a4;
  }
  __syncthreads();

  const float sc = scale[0];
  const int wv = tid >> 6, ln = tid & 63;
  const int q0 = hq * 38;
  const int q1 = (hq == 0) ? 38 : 75;

  for (int q = q0 + wv; q < q1; q += 4) {
    const float* Q = query + ((size_t)b * NQ + q) * DIM;
    float a0 = 0.f, a1 = 0.f, a2 = 0.f, a3 = 0.f, a4 = 0.f;
#pragma unroll
    for (int c = 0; c < 10; ++c) {
      int d4 = (c * 64 + ln) * 4;
      float4 qv = *(const float4*)(Q + d4);
      float4 w0 = *(const float4*)&wsb[0][d4];
      float4 w1 = *(const float4*)&wsb[1][d4];
      float4 w2 = *(const float4*)&wsb[2][d4];
      float4 w3 = *(const float4*)&wsb[3][d4];
      float4 w4 = *(const float4*)&wsb[4][d4];
      DOT4(a0, qv, w0); DOT4(a1, qv, w1); DOT4(a2, qv, w2); DOT4(a3, qv, w3); DOT4(a4, qv, w4);
    }
#pragma unroll
    for (int off = 32; off; off >>= 1) {
      a0 += __shfl_xor(a0, off); a1 += __shfl_xor(a1, off); a2 += __shfl_xor(a2, off);
      a3 += __shfl_xor(a3, off); a4 += __shfl_xor(a4, off);
    }
    if (ln == 0) {
      float* O = out + ((size_t)b * NQ + q) * NWAY;
      O[0] = sc*a0; O[1] = sc*a1; O[2] = sc*a2; O[3] = sc*a3; O[4] = sc*a4;
    }
  }
}

// ---------------------------------------------------------------------------
extern "C" void kernel_launch(void* const* d_in, const int* in_sizes, int n_in,
                              void* d_out, int out_size, void* d_ws, size_t ws_size,
                              hipStream_t stream) {
  (void)in_sizes; (void)n_in; (void)out_size;
  const float* query   = (const float*)d_in[0];
  const float* support = (const float*)d_in[1];
  const float* scale   = (const float*)d_in[2];
  const int*   labels  = (const int*)d_in[3];
  float* out = (float*)d_out;

  float* Kpart = (float*)d_ws;                       // [2][B][625]
  float* zsol  = Kpart + 2 * BB * 625;               // [B][125]
  float* wsbuf = zsol + BB * NTOT;                   // [B][5][2560]
  const size_t need = (size_t)(2*BB*625 + BB*NTOT + BB*NWAY*DIM) * 4;

  dim3 gA(BB, 2);
  k_gram<<<gA, 256, 0, stream>>>(support, Kpart);

  qp_solve3<<<dim3(BB), 192, 0, stream>>>(Kpart, labels, zsol);

  if (ws_size >= need) {
    k_ws<<<dim3(BB), 256, 0, stream>>>(support, zsol, wsbuf);
    k_logits2<<<dim3(BB, 5), 256, 0, stream>>>(query, scale, wsbuf, out);
  } else {
    k_logits<<<dim3(BB, 2), 256, 0, stream>>>(support, query, scale, zsol, out);
  }
}

// Round 6
// 475.678 us; speedup vs baseline: 1.3146x; 1.1711x over previous
//
#include <hip/hip_runtime.h>
#include <utility>

constexpr int BB   = 128;   // batch
constexpr int NSUP = 25;    // support samples
constexpr int NWAY = 5;
constexpr int NTOT = 125;   // NSUP*NWAY
constexpr int NQ   = 75;
constexpr int DIM  = 2560;
constexpr int MAXIT = 15;

#define FMA4(acc, zz, v)                     \
  acc.x = fmaf(zz, v.x, acc.x);              \
  acc.y = fmaf(zz, v.y, acc.y);              \
  acc.z = fmaf(zz, v.z, acc.z);              \
  acc.w = fmaf(zz, v.w, acc.w)

#define DOT4(a, u, vv) a += u.x*vv.x + u.y*vv.y + u.z*vv.z + u.w*vv.w

// ---------------------------------------------------------------------------
// helpers
// ---------------------------------------------------------------------------
__device__ __forceinline__ float frcp(float x) {
#if __has_builtin(__builtin_amdgcn_rcpf)
  return __builtin_amdgcn_rcpf(x);   // v_rcp_f32, ~1 ulp — fine inside IPM
#else
  return 1.0f / x;
#endif
}

// ds_swizzle broadcast of lane K within each 32-lane group.
template <int IMM>
__device__ __forceinline__ float swzb(float v) {
  return __uint_as_float(
      (unsigned)__builtin_amdgcn_ds_swizzle((int)__float_as_uint(v), IMM));
}
template <int K>
__device__ __forceinline__ float bcast32(float v) {
  return swzb<(K << 5)>(v);
}

__device__ __forceinline__ float bfly_sum(float v) {
#pragma unroll
  for (int m = 32; m; m >>= 1) v += __shfl_xor(v, m);
  return v;
}
__device__ __forceinline__ float bfly_min(float v) {
#pragma unroll
  for (int m = 32; m; m >>= 1) v = fminf(v, __shfl_xor(v, m));
  return v;
}

// Batched broadcast fills: all 25 ds_swizzles issued into a live array so the
// compiler can emit them back-to-back with ONE lgkmcnt wait (needs the high
// VGPR budget from __launch_bounds__(192,1)).
template <int K, int... Is>
__device__ __forceinline__ void gj_fill(float (&f)[25], const float (&R)[25],
                                        std::integer_sequence<int, Is...>) {
  ((f[Is] = bcast32<K>(R[Is])), ...);
}
template <int... Ms>
__device__ __forceinline__ void xfill(float (&f)[25], float x,
                                      std::integer_sequence<int, Ms...>) {
  ((f[Ms] = bcast32<Ms>(x)), ...);
}

// One Gauss-Jordan pivot step, column-per-lane in each 32-lane half.
template <int K>
__device__ __forceinline__ void gj_step(float (&R)[25], int j) {
  float f[25];
  gj_fill<K>(f, R, std::make_integer_sequence<int, 25>{});
  float pinv = frcp(f[K]);
  bool  piv  = (j == K);
  float ph   = piv ? pinv : R[K] * pinv;
#pragma unroll
  for (int i = 0; i < 25; ++i) {
    if (i == K) continue;
    float base = piv ? 0.0f : R[i];
    R[i] = fmaf(-f[i], ph, base);
  }
  R[K] = ph;
}
template <int... Ks>
__device__ __forceinline__ void gj25_all(float (&R)[25], int j,
                                         std::integer_sequence<int, Ks...>) {
  (gj_step<Ks>(R, j), ...);
}
__device__ __forceinline__ void gj25(float (&R)[25], int j) {
  gj25_all(R, j, std::make_integer_sequence<int, 25>{});
}

// y = sum_m row[m] * x[lane m of my half] — batched bcasts + 5-way tree sum.
__device__ __forceinline__ float mv25(const float (&row)[25], float x) {
  float f[25];
  xfill(f, x, std::make_integer_sequence<int, 25>{});
  float a0 = 0.f, a1 = 0.f, a2 = 0.f, a3 = 0.f, a4 = 0.f;
#pragma unroll
  for (int m = 0; m < 5; ++m) {
    a0 = fmaf(row[m],      f[m],      a0);
    a1 = fmaf(row[5 + m],  f[5 + m],  a1);
    a2 = fmaf(row[10 + m], f[10 + m], a2);
    a3 = fmaf(row[15 + m], f[15 + m], a3);
    a4 = fmaf(row[20 + m], f[20 + m], a4);
  }
  return ((a0 + a1) + (a2 + a3)) + a4;
}

// ---------------------------------------------------------------------------
// Kernel A: K[b] = support[b] @ support[b]^T, split over 2 d-halves.
// ---------------------------------------------------------------------------
__global__ __launch_bounds__(256) void k_gram(const float* __restrict__ sup,
                                              float* __restrict__ Kpart) {
  const int b    = blockIdx.x;
  const int half = blockIdx.y;
  const int tid  = threadIdx.x;
  const int wv   = tid >> 6;
  const int ln   = tid & 63;

  __shared__ float tile[28][260];
  __shared__ float accb[4][49][16];

  for (int c = tid; c < 3 * 260; c += 256) tile[25 + c / 260][c % 260] = 0.0f;

  const float* S = sup + (size_t)b * NSUP * DIM + half * 1280;

  float acc[4][4];
#pragma unroll
  for (int x = 0; x < 4; ++x)
#pragma unroll
    for (int y = 0; y < 4; ++y) acc[x][y] = 0.0f;

  const int ti = ln / 7, tj = ln % 7;
  const int i0 = 4 * ti, j0 = 4 * tj;

  for (int ch = 0; ch < 5; ++ch) {
    __syncthreads();
    for (int q = tid; q < 1600; q += 256) {
      int rr = q >> 6, c4 = q & 63;
      float4 v = *(const float4*)(S + rr * DIM + ch * 256 + 4 * c4);
      *(float4*)&tile[rr][4 * c4] = v;
    }
    __syncthreads();
    if (ln < 49) {
#pragma unroll
      for (int c = 0; c < 16; ++c) {
        const int d4 = (wv * 16 + c) * 4;
        float4 av[4], bv[4];
#pragma unroll
        for (int x = 0; x < 4; ++x) av[x] = *(const float4*)&tile[i0 + x][d4];
#pragma unroll
        for (int y = 0; y < 4; ++y) bv[y] = *(const float4*)&tile[j0 + y][d4];
#pragma unroll
        for (int x = 0; x < 4; ++x)
#pragma unroll
          for (int y = 0; y < 4; ++y) {
            acc[x][y] += av[x].x * bv[y].x + av[x].y * bv[y].y +
                         av[x].z * bv[y].z + av[x].w * bv[y].w;
          }
      }
    }
  }

  if (ln < 49) {
#pragma unroll
    for (int x = 0; x < 4; ++x)
#pragma unroll
      for (int y = 0; y < 4; ++y) accb[wv][ln][x * 4 + y] = acc[x][y];
  }
  __syncthreads();

  for (int p = tid; p < 625; p += 256) {
    int i = p / 25, jx = p % 25;
    int lx = (i / 4) * 7 + (jx / 4);
    int sx = (i % 4) * 4 + (jx % 4);
    float v = accb[0][lx][sx] + accb[1][lx][sx] + accb[2][lx][sx] + accb[3][lx][sx];
    Kpart[((size_t)half * BB + b) * 625 + p] = v;
  }
}

// ---------------------------------------------------------------------------
// Kernel B: Mehrotra IPM, one block (192 threads = 3 waves) per batch element.
// Wave q owns matrices {2q, 2q+1} in its two 32-lane halves (wave 2: m4
// duplicated). Broadcasts via batched ds_swizzle; 7 barriers per iteration.
// __launch_bounds__(192,1): only 3 waves ever resident -> give the register
// allocator the full budget so the 25-swizzle batches stay live at once.
// ---------------------------------------------------------------------------
__global__ __launch_bounds__(192, 1) void qp_solve4(const float* __restrict__ Kpart,
                                                    const int* __restrict__ labels,
                                                    float* __restrict__ zout) {
  const int b   = blockIdx.x;
  const int tid = threadIdx.x;
  const int wq  = tid >> 6;          // wave 0..2
  const int l   = tid & 63;
  const int h   = l >> 5;
  const int j   = l & 31;
  const bool act = (j < 25);
  const int jc  = act ? j : 0;
  const int matW = (wq == 2) ? 4 : 2 * wq + h;
  const bool cnt = act && !(wq == 2 && h == 1);   // unique (sample, way) owner

  __shared__ float Klds[25][26];
  __shared__ float Wlds[5][25][26];   // H_w^{-1}
  __shared__ float SL[25][26];        // S^{-1}
  __shared__ float Vb[5][28];
  __shared__ float Zl[5][28];
  __shared__ float NUl[28];
  __shared__ float MU[4], AA[4], PP[4], CC[4];

  for (int p = tid; p < 625; p += 192)
    Klds[p / 25][p % 25] =
        Kpart[(size_t)b * 625 + p] + Kpart[(size_t)(BB + b) * 625 + p];

  int lab = labels[b * 25 + jc];
  float oh = (lab == matW) ? 1.0f : 0.0f;
  float e_ = -oh;
  float z_ = 0.1f * oh - 1.0f;   // h - 1
  float s_ = 1.0f, lm_ = 1.0f;

  if (wq == 0 && h == 0 && act) NUl[jc] = 0.0f;
  if (cnt) Zl[matW][jc] = z_;
  {
    float sl = cnt ? s_ * lm_ : 0.0f;
    sl = bfly_sum(sl);
    if (l == 0) MU[wq] = sl;
  }
  __syncthreads();

  float Kc[25];   // K column jc (K symmetric -> also row jc)
#pragma unroll
  for (int i = 0; i < 25; ++i) Kc[i] = Klds[i][jc];

  float R[25], Wrow[25], Srow[25];

#pragma unroll 1
  for (int it = 0; it < MAXIT; ++it) {
    // ---- residuals ----
    float mu = (MU[0] + MU[1] + MU[2]) * (1.0f / 125.0f);
    float rp = Zl[0][jc] + Zl[1][jc] + Zl[2][jc] + Zl[3][jc] + Zl[4][jc];
    float nu = NUl[jc];
    float d_ = lm_ / s_;
    float kz = mv25(Kc, z_);
    float rd = kz + z_ + e_ + lm_ + nu;
    float rhs1 = lm_ - rd;                   // -r_d + lam

    // ---- H = K + I + diag(lam/s); invert (batched-swizzle GJ) ----
#pragma unroll
    for (int i = 0; i < 25; ++i) R[i] = Kc[i] + ((j == i) ? (1.0f + d_) : 0.0f);
    gj25(R, j);
    if (cnt) {
#pragma unroll
      for (int i = 0; i < 25; ++i) Wlds[matW][i][jc] = R[i];
    }
    __syncthreads();                          // B_A: W published

    // W row into registers; predictor v1 = W rhs1
#pragma unroll
    for (int m = 0; m < 25; ++m) Wrow[m] = Wlds[matW][jc][m];
    float v1 = mv25(Wrow, rhs1);
    if (cnt) Vb[matW][jc] = v1;

    // S = sum_w W_w ; invert (wave 0 only)
    if (wq == 0) {
#pragma unroll
      for (int i = 0; i < 25; ++i)
        R[i] = Wlds[0][i][jc] + Wlds[1][i][jc] + Wlds[2][i][jc] +
               Wlds[3][i][jc] + Wlds[4][i][jc];
      gj25(R, j);
      if (h == 0 && act) {
#pragma unroll
        for (int i = 0; i < 25; ++i) SL[i][jc] = R[i];
      }
    }
    __syncthreads();                          // B_B: Sinv + Vb ready
#pragma unroll
    for (int m = 0; m < 25; ++m) Srow[m] = SL[jc][m];

    // ---- predictor ----
    float u = Vb[0][jc] + Vb[1][jc] + Vb[2][jc] + Vb[3][jc] + Vb[4][jc];
    float t = u + rp;
    float dn1 = mv25(Srow, t);
    float r2 = rhs1 - dn1;
    float dz1 = mv25(Wrow, r2);
    float ds1 = -dz1;
    float dl1 = fmaf(d_, dz1, -lm_);
    float cand = 1.0f;
    if (act) {
      if (ds1 < 0.0f) cand = fminf(cand, -s_ / ds1);
      if (dl1 < 0.0f) cand = fminf(cand, -lm_ / dl1);
    }
    cand = bfly_min(cand);
    if (l == 0) AA[wq] = cand;
    __syncthreads();                          // B_C
    float a_aff = fminf(AA[0], fminf(AA[1], AA[2]));
    float pr = cnt ? (s_ + a_aff * ds1) * (lm_ + a_aff * dl1) : 0.0f;
    pr = bfly_sum(pr);
    if (l == 0) PP[wq] = pr;
    __syncthreads();                          // B_D
    float mu_aff = (PP[0] + PP[1] + PP[2]) * (1.0f / 125.0f);
    float rt = mu_aff / mu;
    float sg = rt * rt * rt * mu;

    // ---- corrector ----
    float rc = sg - ds1 * dl1;
    float rhsc = lm_ - rd - rc / s_;
    float v2 = mv25(Wrow, rhsc);
    if (cnt) Vb[matW][jc] = v2;
    __syncthreads();                          // B_E
    float u2 = Vb[0][jc] + Vb[1][jc] + Vb[2][jc] + Vb[3][jc] + Vb[4][jc];
    float t2 = u2 + rp;
    float dn2 = mv25(Srow, t2);
    float r2c = rhsc - dn2;
    float dz2 = mv25(Wrow, r2c);
    float ds2 = -dz2;
    float dl2 = rc / s_ - lm_ + d_ * dz2;
    float c2 = 1.0f;
    if (act) {
      if (ds2 < 0.0f) c2 = fminf(c2, -s_ / ds2);
      if (dl2 < 0.0f) c2 = fminf(c2, -lm_ / dl2);
    }
    c2 = bfly_min(c2);
    if (l == 0) CC[wq] = c2;
    __syncthreads();                          // B_F
    float a = 0.995f * fminf(CC[0], fminf(CC[1], CC[2]));

    // ---- update ----
    z_  = fmaf(a, dz2, z_);
    s_  = fmaf(a, ds2, s_);
    lm_ = fmaf(a, dl2, lm_);
    if (wq == 0 && h == 0 && act) NUl[jc] = nu + a * dn2;
    if (cnt) Zl[matW][jc] = z_;
    {
      float sl = cnt ? s_ * lm_ : 0.0f;
      sl = bfly_sum(sl);
      if (l == 0) MU[wq] = sl;
    }
    __syncthreads();                          // B_G (= top of next iter)
  }

  if (cnt) zout[(size_t)b * NTOT + jc * 5 + matW] = z_;
}

// ---------------------------------------------------------------------------
// Kernel C1: ws[b][w][d] = sum_s z[s,w] * support[s][d]
// ---------------------------------------------------------------------------
__global__ __launch_bounds__(256) void k_ws(const float* __restrict__ sup,
                                            const float* __restrict__ zsol,
                                            float* __restrict__ ws) {
  const int b   = blockIdx.x;
  const int tid = threadIdx.x;
  __shared__ float zsh[NTOT];
  if (tid < NTOT) zsh[tid] = zsol[(size_t)b * NTOT + tid];
  __syncthreads();

  const float* Sb = sup + (size_t)b * NSUP * DIM;
  for (int d4 = tid; d4 < 640; d4 += 256) {
    float4 a0 = {0,0,0,0}, a1 = {0,0,0,0}, a2 = {0,0,0,0}, a3 = {0,0,0,0}, a4 = {0,0,0,0};
#pragma unroll
    for (int s = 0; s < 25; ++s) {
      float4 v = *(const float4*)(Sb + s * DIM + 4 * d4);
      float z0 = zsh[s*5+0], z1 = zsh[s*5+1], z2 = zsh[s*5+2], z3 = zsh[s*5+3], z4 = zsh[s*5+4];
      FMA4(a0, z0, v); FMA4(a1, z1, v); FMA4(a2, z2, v); FMA4(a3, z3, v); FMA4(a4, z4, v);
    }
    float* W = ws + (size_t)b * NWAY * DIM;
    *(float4*)(W + 0*DIM + 4*d4) = a0;
    *(float4*)(W + 1*DIM + 4*d4) = a1;
    *(float4*)(W + 2*DIM + 4*d4) = a2;
    *(float4*)(W + 3*DIM + 4*d4) = a3;
    *(float4*)(W + 4*DIM + 4*d4) = a4;
  }
}

// ---------------------------------------------------------------------------
// Kernel C2: logits[b][q][w] = scale * dot(query[b][q], ws[b][w])
// ---------------------------------------------------------------------------
__global__ __launch_bounds__(256) void k_logits2(const float* __restrict__ query,
                                                 const float* __restrict__ scale,
                                                 const float* __restrict__ ws,
                                                 float* __restrict__ out) {
  const int b   = blockIdx.x;
  const int qt  = blockIdx.y;
  const int tid = threadIdx.x;
  const int wv  = tid >> 6, ln = tid & 63;

  __shared__ float wsb[5][2564];
  for (int p = tid; p < 3200; p += 256) {
    int w = p / 640, c = p % 640;
    *(float4*)&wsb[w][4 * c] = *(const float4*)(ws + ((size_t)b * NWAY + w) * DIM + 4 * c);
  }
  __syncthreads();

  const float sc = scale[0];
  const int q0 = qt * 15, q1 = q0 + 15;
  for (int q = q0 + wv; q < q1; q += 4) {
    const float* Q = query + ((size_t)b * NQ + q) * DIM;
    float a0 = 0.f, a1 = 0.f, a2 = 0.f, a3 = 0.f, a4 = 0.f;
#pragma unroll
    for (int c = 0; c < 10; ++c) {
      int d4 = (c * 64 + ln) * 4;
      float4 qv = *(const float4*)(Q + d4);
      float4 w0 = *(const float4*)&wsb[0][d4];
      float4 w1 = *(const float4*)&wsb[1][d4];
      float4 w2 = *(const float4*)&wsb[2][d4];
      float4 w3 = *(const float4*)&wsb[3][d4];
      float4 w4 = *(const float4*)&wsb[4][d4];
      DOT4(a0, qv, w0); DOT4(a1, qv, w1); DOT4(a2, qv, w2); DOT4(a3, qv, w3); DOT4(a4, qv, w4);
    }
#pragma unroll
    for (int off = 32; off; off >>= 1) {
      a0 += __shfl_xor(a0, off); a1 += __shfl_xor(a1, off); a2 += __shfl_xor(a2, off);
      a3 += __shfl_xor(a3, off); a4 += __shfl_xor(a4, off);
    }
    if (ln == 0) {
      float* O = out + ((size_t)b * NQ + q) * NWAY;
      O[0] = sc*a0; O[1] = sc*a1; O[2] = sc*a2; O[3] = sc*a3; O[4] = sc*a4;
    }
  }
}

// ---------------------------------------------------------------------------
// Fallback fused logits (if workspace too small for ws buffer)
// ---------------------------------------------------------------------------
__global__ __launch_bounds__(256) void k_logits(const float* __restrict__ sup,
                                                const float* __restrict__ query,
                                                const float* __restrict__ scale,
                                                const float* __restrict__ zsol,
                                                float* __restrict__ out) {
  const int b   = blockIdx.x;
  const int hq  = blockIdx.y;
  const int tid = threadIdx.x;

  __shared__ float wsb[5][2564];
  __shared__ float zsh[128];

  if (tid < NTOT) zsh[tid] = zsol[(size_t)b * NTOT + tid];
  __syncthreads();

  const float* Sb = sup + (size_t)b * NSUP * DIM;
  for (int d4 = tid; d4 < 640; d4 += 256) {
    float4 a0 = {0,0,0,0}, a1 = {0,0,0,0}, a2 = {0,0,0,0}, a3 = {0,0,0,0}, a4 = {0,0,0,0};
#pragma unroll
    for (int s = 0; s < 25; ++s) {
      float4 v = *(const float4*)(Sb + s * DIM + 4 * d4);
      float z0 = zsh[s*5+0], z1 = zsh[s*5+1], z2 = zsh[s*5+2], z3 = zsh[s*5+3], z4 = zsh[s*5+4];
      FMA4(a0, z0, v); FMA4(a1, z1, v); FMA4(a2, z2, v); FMA4(a3, z3, v); FMA4(a4, z4, v);
    }
    *(float4*)&wsb[0][4*d4] = a0; *(float4*)&wsb[1][4*d4] = a1; *(float4*)&wsb[2][4*d4] = a2;
    *(float4*)&wsb[3][4*d4] = a3; *(float4*)&wsb[4][4*d4] = a4;
  }
  __syncthreads();

  const float sc = scale[0];
  const int wv = tid >> 6, ln = tid & 63;
  const int q0 = hq * 38;
  const int q1 = (hq == 0) ? 38 : 75;

  for (int q = q0 + wv; q < q1; q += 4) {
    const float* Q = query + ((size_t)b * NQ + q) * DIM;
    float a0 = 0.f, a1 = 0.f, a2 = 0.f, a3 = 0.f, a4 = 0.f;
#pragma unroll
    for (int c = 0; c < 10; ++c) {
      int d4 = (c * 64 + ln) * 4;
      float4 qv = *(const float4*)(Q + d4);
      float4 w0 = *(const float4*)&wsb[0][d4];
      float4 w1 = *(const float4*)&wsb[1][d4];
      float4 w2 = *(const float4*)&wsb[2][d4];
      float4 w3 = *(const float4*)&wsb[3][d4];
      float4 w4 = *(const float4*)&wsb[4][d4];
      DOT4(a0, qv, w0); DOT4(a1, qv, w1); DOT4(a2, qv, w2); DOT4(a3, qv, w3); DOT4(a4, qv, w4);
    }
#pragma unroll
    for (int off = 32; off; off >>= 1) {
      a0 += __shfl_xor(a0, off); a1 += __shfl_xor(a1, off); a2 += __shfl_xor(a2, off);
      a3 += __shfl_xor(a3, off); a4 += __shfl_xor(a4, off);
    }
    if (ln == 0) {
      float* O = out + ((size_t)b * NQ + q) * NWAY;
      O[0] = sc*a0; O[1] = sc*a1; O[2] = sc*a2; O[3] = sc*a3; O[4] = sc*a4;
    }
  }
}

// ---------------------------------------------------------------------------
extern "C" void kernel_launch(void* const* d_in, const int* in_sizes, int n_in,
                              void* d_out, int out_size, void* d_ws, size_t ws_size,
                              hipStream_t stream) {
  (void)in_sizes; (void)n_in; (void)out_size;
  const float* query   = (const float*)d_in[0];
  const float* support = (const float*)d_in[1];
  const float* scale   = (const float*)d_in[2];
  const int*   labels  = (const int*)d_in[3];
  float* out = (float*)d_out;

  float* Kpart = (float*)d_ws;                       // [2][B][625]
  float* zsol  = Kpart + 2 * BB * 625;               // [B][125]
  float* wsbuf = zsol + BB * NTOT;                   // [B][5][2560]
  const size_t need = (size_t)(2*BB*625 + BB*NTOT + BB*NWAY*DIM) * 4;

  dim3 gA(BB, 2);
  k_gram<<<gA, 256, 0, stream>>>(support, Kpart);

  qp_solve4<<<dim3(BB), 192, 0, stream>>>(Kpart, labels, zsol);

  if (ws_size >= need) {
    k_ws<<<dim3(BB), 256, 0, stream>>>(support, zsol, wsbuf);
    k_logits2<<<dim3(BB, 5), 256, 0, stream>>>(query, scale, wsbuf, out);
  } else {
    k_logits<<<dim3(BB, 2), 256, 0, stream>>>(support, query, scale, zsol, out);
  }
}